// Round 1
// 372.572 us; speedup vs baseline: 1.0490x; 1.0490x over previous
//
#include <hip/hip_runtime.h>

#define B_ 8
#define M_ 4096
#define W_ 128
#define C_ 32
#define NN_ 16

typedef short s16x8 __attribute__((ext_vector_type(8)));
typedef float f32x4 __attribute__((ext_vector_type(4)));

static __device__ __forceinline__ unsigned short f2bf(float f) {
  unsigned u = __builtin_bit_cast(unsigned, f);
  u = u + 0x7FFFu + ((u >> 16) & 1u);   // RNE
  return (unsigned short)(u >> 16);
}
static __device__ __forceinline__ s16x8 cvt8v(float4 a, float4 b) {
  s16x8 r;
  r[0] = (short)f2bf(a.x); r[1] = (short)f2bf(a.y);
  r[2] = (short)f2bf(a.z); r[3] = (short)f2bf(a.w);
  r[4] = (short)f2bf(b.x); r[5] = (short)f2bf(b.y);
  r[6] = (short)f2bf(b.z); r[7] = (short)f2bf(b.w);
  return r;
}
static __device__ __forceinline__ float safeexp(float a) {
  return expf(fminf(a, 87.f));
}

// ---------------------------------------------------------------- poison (diagnostic sentinel)
__global__ void poison_kernel(float* __restrict__ out, int n, float val) {
  int t = blockIdx.x * blockDim.x + threadIdx.x;
  if (t < n) out[t] = val;
}

// ---------------------------------------------------------------- init: fc1acc = fc1b; bn slots = 0
__global__ __launch_bounds__(256) void init_kernel(
    float* __restrict__ fc1acc, const float* __restrict__ fc1b,
    float* __restrict__ bn) {
  int g = blockIdx.x * 256 + threadIdx.x;
  if (g < 2048) fc1acc[g] = fc1b[g & 255];
  else if (g < 34816) bn[g - 2048] = 0.f;
}

// ---------------------------------------------------------------- attention: one THREAD per row (proven)
__global__ __launch_bounds__(256) void attn_kernel(
    const float* __restrict__ pseudo, const int* __restrict__ Lidx,
    const float* __restrict__ edge_w, const float* __restrict__ edge_b,
    const float* __restrict__ mu0, const float* __restrict__ sg0,
    const float* __restrict__ mu1, const float* __restrict__ sg1,
    float* __restrict__ we0, float* __restrict__ we1, int* __restrict__ colb) {
  int m = blockIdx.x * 256 + threadIdx.x;
  if (m >= M_) return;
  float w0[NN_], w1[NN_];
  int col[NN_];
#pragma unroll
  for (int n = 0; n < NN_; n++) {
    int e = m * NN_ + n;
    float p0 = pseudo[e * 2], p1 = pseudo[e * 2 + 1];
    float emb[5];
#pragma unroll
    for (int d = 0; d < 5; d++)
      emb[d] = p0 * edge_w[d * 2] + p1 * edge_w[d * 2 + 1] + edge_b[d];
    float a0 = 0.f, a1 = 0.f;
#pragma unroll
    for (int j = 0; j < 4; j++) {
      float qa = 0.f, qb = 0.f;
#pragma unroll
      for (int d = 0; d < 5; d++) {
        float u0 = emb[d] - mu0[j * 5 + d];
        qa += u0 * u0 * sg0[j * 5 + d];
        float u1 = emb[d] - mu1[j * 5 + d];
        qb += u1 * u1 * sg1[j * 5 + d];
      }
      a0 += safeexp(-0.5f * qa);
      a1 += safeexp(-0.5f * qb);
    }
    w0[n] = a0; w1[n] = a1;
    col[n] = Lidx[e] % M_;
  }
  float mx0 = w0[0], mx1 = w1[0];
#pragma unroll
  for (int n = 1; n < NN_; n++) { mx0 = fmaxf(mx0, w0[n]); mx1 = fmaxf(mx1, w1[n]); }
  float s0 = 0.f, s1 = 0.f;
#pragma unroll
  for (int n = 0; n < NN_; n++) {
    w0[n] = safeexp(w0[n] - mx0); s0 += w0[n];
    w1[n] = safeexp(w1[n] - mx1); s1 += w1[n];
  }
  float r0 = 1.f / s0, r1 = 1.f / s1;
#pragma unroll
  for (int n = 0; n < NN_; n++) {
    bool last = true;                       // numpy fancy-set: last duplicate wins
#pragma unroll
    for (int n2 = n + 1; n2 < NN_; n2++)
      if (col[n2] == col[n]) last = false;
    int e = m * NN_ + n;
    we0[e] = last ? w0[n] * r0 : 0.f;
    we1[e] = last ? w1[n] * r1 : 0.f;
    colb[e] = col[n];
  }
}

// ---------------------------------------------------------------- proj0 (MFMA): G[r][0:32]=x@l1w0.T, G[r][32:64]=x@l2w0.T
__global__ __launch_bounds__(256) void proj0_kernel(
    const float* __restrict__ x, const float* __restrict__ l1w0,
    const float* __restrict__ l2w0, float* __restrict__ G) {
  int lane = threadIdx.x & 63, wave = threadIdx.x >> 6;
  int l16 = lane & 15, quad = lane >> 4;
  int tile = blockIdx.x * 4 + wave;            // 2048 tiles of 16 rows
  s16x8 bf[4][4];
#pragma unroll
  for (int kit = 0; kit < 4; kit++) {
#pragma unroll
    for (int ct = 0; ct < 4; ct++) {
      int out = ct * 16 + l16;                 // 0..63
      const float* src = (out < 32 ? l1w0 + out * 128 : l2w0 + (out - 32) * 128)
                         + kit * 32 + quad * 8;
      bf[kit][ct] = cvt8v(*(const float4*)src, *(const float4*)(src + 4));
    }
  }
  f32x4 acc[4];
#pragma unroll
  for (int ct = 0; ct < 4; ct++) acc[ct] = (f32x4){0.f, 0.f, 0.f, 0.f};
  int row = tile * 16 + l16;
  const float* xr = x + (size_t)row * 128 + quad * 8;
#pragma unroll
  for (int kit = 0; kit < 4; kit++) {
    const float* ap = xr + kit * 32;
    s16x8 a = cvt8v(*(const float4*)ap, *(const float4*)(ap + 4));
#pragma unroll
    for (int ct = 0; ct < 4; ct++)
      acc[ct] = __builtin_amdgcn_mfma_f32_16x16x32_bf16(a, bf[kit][ct], acc[ct], 0, 0, 0);
  }
  int rbase = tile * 16 + quad * 4;            // C/D: col=lane&15, row=quad*4+i (m89)
#pragma unroll
  for (int ct = 0; ct < 4; ct++)
#pragma unroll
    for (int i = 0; i < 4; i++)
      G[(size_t)(rbase + i) * 64 + ct * 16 + l16] = acc[ct][i];
}

// ---------------------------------------------------------------- conv (shared for both layers):
// h = L.G1 + G2 + b1 + b2; BN partials via LDS reduction.
// Block = 8 rows x 32 ch. Stage (we,col) in LDS -> 16 independent gathers in flight.
__global__ __launch_bounds__(256) void conv_kernel(
    const float* __restrict__ G,
    const float* __restrict__ we, const int* __restrict__ colb,
    const float* __restrict__ b1c, const float* __restrict__ b2c,
    float* __restrict__ h, float* __restrict__ bns, float* __restrict__ bnq) {
  __shared__ float s_we[8][16];
  __shared__ int   s_cn[8][16];
  __shared__ float s_s[32], s_q[32];
  int tid = threadIdx.x;
  if (tid < 128) {
    int row = tid >> 4, nn = tid & 15;
    int m = (blockIdx.x * 8 + row) & 4095;     // attn arrays are per-m (batch-independent)
    s_we[row][nn] = we[m * 16 + nn];
    s_cn[row][nn] = colb[m * 16 + nn];
  } else if (tid < 160) {
    s_s[tid - 128] = 0.f;
    s_q[tid - 128] = 0.f;
  }
  __syncthreads();
  int row = tid >> 5, c = tid & 31;
  int r = blockIdx.x * 8 + row;
  int b = r >> 12;
  const float* Gb = G + ((size_t)b << 18);     // b*4096*64
  float acc = 0.f;
#pragma unroll
  for (int nn = 0; nn < NN_; nn++)             // all 16 loads independent -> in flight together
    acc += s_we[row][nn] * Gb[s_cn[row][nn] * 64 + c];
  float hv = acc + G[(size_t)r * 64 + 32 + c] + b1c[c] + b2c[c];
  h[(size_t)r * 32 + c] = hv;
  atomicAdd(&s_s[c], hv);                      // LDS atomic (ds_add_f32), 8-way per addr
  atomicAdd(&s_q[c], hv * hv);
  __syncthreads();
  if (tid < 32) {
    int slot = blockIdx.x & 255;
    atomicAdd(&bns[tid * 256 + slot], s_s[tid]);
    atomicAdd(&bnq[tid * 256 + slot], s_q[tid]);
  }
}

// ---------------------------------------------------------------- BN finalize (sum 256 slots)
__global__ void bnfin_kernel(const float* __restrict__ bns, const float* __restrict__ bnq,
                             const float* __restrict__ g, const float* __restrict__ bb,
                             float* __restrict__ scale, float* __restrict__ shift) {
  int c = threadIdx.x;
  if (c >= 32) return;
  float s = 0.f, q = 0.f;
  for (int i = 0; i < 256; i++) { s += bns[c * 256 + i]; q += bnq[c * 256 + i]; }
  float mean = s * (1.f / 32768.f);
  float var = fmaxf(q * (1.f / 32768.f) - mean * mean, 0.f);
  float sc = g[c] * rsqrtf(var + 1e-5f);
  scale[c] = sc;
  shift[c] = bb[c] - mean * sc;
}

// ---------------------------------------------------------------- proj1 (MFMA, K=32): a=relu(bn0(h0)); G=[a@l1w1.T | a@l2w1.T]
__global__ __launch_bounds__(256) void proj1_kernel(
    const float* __restrict__ h0, const float* __restrict__ sc0,
    const float* __restrict__ l1w1, const float* __restrict__ l2w1,
    float* __restrict__ G) {
  int lane = threadIdx.x & 63, wave = threadIdx.x >> 6;
  int l16 = lane & 15, quad = lane >> 4;
  int tile = blockIdx.x * 4 + wave;
  s16x8 bf[4];
#pragma unroll
  for (int ct = 0; ct < 4; ct++) {
    int out = ct * 16 + l16;
    const float* src = (out < 32 ? l1w1 + out * 32 : l2w1 + (out - 32) * 32) + quad * 8;
    bf[ct] = cvt8v(*(const float4*)src, *(const float4*)(src + 4));
  }
  float scv[8], shv[8];
#pragma unroll
  for (int j = 0; j < 8; j++) {
    scv[j] = sc0[quad * 8 + j];
    shv[j] = sc0[32 + quad * 8 + j];
  }
  int row = tile * 16 + l16;
  const float* hr = h0 + (size_t)row * 32 + quad * 8;
  float4 hv0 = *(const float4*)hr;
  float4 hv1 = *(const float4*)(hr + 4);
  float av[8] = {hv0.x, hv0.y, hv0.z, hv0.w, hv1.x, hv1.y, hv1.z, hv1.w};
  s16x8 a;
#pragma unroll
  for (int j = 0; j < 8; j++)
    a[j] = (short)f2bf(fmaxf(av[j] * scv[j] + shv[j], 0.f));
  f32x4 acc[4];
#pragma unroll
  for (int ct = 0; ct < 4; ct++) {
    f32x4 z = {0.f, 0.f, 0.f, 0.f};
    acc[ct] = __builtin_amdgcn_mfma_f32_16x16x32_bf16(a, bf[ct], z, 0, 0, 0);
  }
  int rbase = tile * 16 + quad * 4;
#pragma unroll
  for (int ct = 0; ct < 4; ct++)
#pragma unroll
    for (int i = 0; i < 4; i++)
      G[(size_t)(rbase + i) * 64 + ct * 16 + l16] = acc[ct][i];
}

// ---------------------------------------------------------------- fc1: block=(kc,og); ALL 8 batches -> fc1w read ONCE
// Spill fix: waves_per_eu(4,4) forces the 128-VGPR budget (was: compiler
// squeezed to 64 VGPRs for 8 waves/EU and spilled ~47 regs/thread to
// scratch -> 47 MB of scratch writebacks per dispatch, 101.8 us).
// Peak live set here ~110: acc[8][8]=64 + w4[8]=32 + h4 + addresses.
__global__ __launch_bounds__(256) __attribute__((amdgpu_waves_per_eu(4, 4)))
void fc1_kernel(
    const float* __restrict__ h1, const float* __restrict__ sc1,
    const float* __restrict__ fc1w, float* __restrict__ fc1acc) {
  __shared__ float a1s[8][1024];
  int kc = blockIdx.x >> 3;                 // 0..127
  int og = blockIdx.x & 7;                  // outputs og*32..og*32+31
  int kbase = kc << 10;
  int obase = og << 5;
  // stage a = relu(bn1(h1)) slice: 2048 float4, 8 per thread
  for (int idx = threadIdx.x; idx < 2048; idx += 256) {
    int b = idx >> 8;
    int kv = (idx & 255) << 2;              // k within the 1024-chunk, %4==0
    int c = kv & 31;                        // channel base, %4==0 (4 | 32)
    float4 hv = *(const float4*)(h1 + ((size_t)b << 17) + kbase + kv);
    float4 scv = *(const float4*)(sc1 + c);
    float4 shv = *(const float4*)(sc1 + 32 + c);
    float4 r;
    r.x = fmaxf(hv.x * scv.x + shv.x, 0.f);
    r.y = fmaxf(hv.y * scv.y + shv.y, 0.f);
    r.z = fmaxf(hv.z * scv.z + shv.z, 0.f);
    r.w = fmaxf(hv.w * scv.w + shv.w, 0.f);
    *(float4*)&a1s[b][kv] = r;
  }
  __syncthreads();
  int lane = threadIdx.x & 63, wave = threadIdx.x >> 6;
  float acc[8][8];                           // [out i][batch b]
#pragma unroll
  for (int i = 0; i < 8; i++)
#pragma unroll
    for (int b = 0; b < 8; b++) acc[i][b] = 0.f;
  const float* wb = fc1w + (size_t)(obase + wave * 8) * 131072 + kbase;
#pragma unroll 1
  for (int it = 0; it < 4; it++) {
    int ko = it * 256 + lane * 4;
    float4 w4[8];                            // 8 independent loads in flight
#pragma unroll
    for (int i = 0; i < 8; i++)
      w4[i] = *(const float4*)(wb + (size_t)i * 131072 + ko);
#pragma unroll
    for (int b = 0; b < 8; b++) {
      float4 h4 = *(const float4*)&a1s[b][ko];
#pragma unroll
      for (int i = 0; i < 8; i++)
        acc[i][b] += w4[i].x * h4.x + w4[i].y * h4.y + w4[i].z * h4.z + w4[i].w * h4.w;
    }
  }
  float myval = 0.f;
#pragma unroll
  for (int i = 0; i < 8; i++) {
#pragma unroll
    for (int b = 0; b < 8; b++) {
      float v = acc[i][b];
#pragma unroll
      for (int off = 1; off < 64; off <<= 1) v += __shfl_xor(v, off);
      if (lane == i * 8 + b) myval = v;
    }
  }
  atomicAdd(&fc1acc[(lane & 7) * 256 + obase + wave * 8 + (lane >> 3)], myval);
}

// ---------------------------------------------------------------- fc2 -> fp32 out
__global__ void fc2_kernel(const float* __restrict__ fc1acc,
                           const float* __restrict__ fc2w,
                           const float* __restrict__ fc2b,
                           float* __restrict__ out) {
  int t = blockIdx.x * blockDim.x + threadIdx.x;
  if (t >= 424) return;
  int b = t / 53, j = t - b * 53;
  float s = fc2b[j];
  const float* fa = fc1acc + b * 256;
  const float* wr = fc2w + j * 256;
#pragma unroll 8
  for (int o = 0; o < 256; o++) s += fmaxf(fa[o], 0.f) * wr[o];
  out[t] = s;
}

// ---------------------------------------------------------------- launch
extern "C" void kernel_launch(void* const* d_in, const int* in_sizes, int n_in,
                              void* d_out, int out_size, void* d_ws, size_t ws_size,
                              hipStream_t stream) {
  float* out = (float*)d_out;
  int bad = 0;
  if (n_in != 25) bad = 2;
  else if (in_sizes[0] != 4194304) bad = 3;
  else if (in_sizes[2] != 65536) bad = 4;
  else if (in_sizes[21] != 33554432) bad = 5;
  else if (out_size != 424) bad = 6;
  else if (ws_size < 13509120) bad = 1;
  if (bad) {
    poison_kernel<<<2, 256, 0, stream>>>(out, out_size, (float)bad * 1.0e6f);
    return;
  }

  const float* x      = (const float*)d_in[0];
  const float* pseudo = (const float*)d_in[1];
  const int*   Lidx   = (const int*)d_in[2];
  const float* edge_w = (const float*)d_in[3];
  const float* edge_b = (const float*)d_in[4];
  const float* mu0    = (const float*)d_in[5];
  const float* sg0    = (const float*)d_in[6];
  const float* mu1    = (const float*)d_in[7];
  const float* sg1    = (const float*)d_in[8];
  const float* l1w0   = (const float*)d_in[9];
  const float* l1b0   = (const float*)d_in[10];
  const float* l2w0   = (const float*)d_in[11];
  const float* l2b0   = (const float*)d_in[12];
  const float* l1w1   = (const float*)d_in[13];
  const float* l1b1   = (const float*)d_in[14];
  const float* l2w1   = (const float*)d_in[15];
  const float* l2b1   = (const float*)d_in[16];
  const float* bng0   = (const float*)d_in[17];
  const float* bnb0   = (const float*)d_in[18];
  const float* bng1   = (const float*)d_in[19];
  const float* bnb1   = (const float*)d_in[20];
  const float* fc1w   = (const float*)d_in[21];
  const float* fc1b   = (const float*)d_in[22];
  const float* fc2w   = (const float*)d_in[23];
  const float* fc2b   = (const float*)d_in[24];

  char* Wp = (char*)d_ws;
  int*   colb   = (int*)  (Wp + 0);          // 65536 i32
  float* we0    = (float*)(Wp + 262144);     // 65536 f32
  float* we1    = (float*)(Wp + 524288);     // 65536 f32
  float* G      = (float*)(Wp + 786432);     // 32768 x 64 f32 (8 MB): [.,0:32]=G1, [.,32:64]=G2
  float* h0     = (float*)(Wp + 9175040);    // 32768 x 32 f32 (4 MB)
  float* h1     = (float*)(Wp + 9175040);    // aliases h0 (h0 dead after proj1)
  float* bn     = (float*)(Wp + 13369344);   // 4 x (32ch x 256 slots) f32
  float* sc     = (float*)(Wp + 13500416);   // scale0,shift0,scale1,shift1
  float* fc1acc = (float*)(Wp + 13500928);   // 8x256 f32

  init_kernel<<<136, 256, 0, stream>>>(fc1acc, fc1b, bn);
  attn_kernel<<<16, 256, 0, stream>>>(pseudo, Lidx, edge_w, edge_b,
                                      mu0, sg0, mu1, sg1, we0, we1, colb);
  proj0_kernel<<<512, 256, 0, stream>>>(x, l1w0, l2w0, G);
  conv_kernel<<<4096, 256, 0, stream>>>(G, we0, colb, l1b0, l2b0,
                                        h0, bn, bn + 8192);
  bnfin_kernel<<<1, 32, 0, stream>>>(bn, bn + 8192, bng0, bnb0, sc, sc + 32);
  proj1_kernel<<<512, 256, 0, stream>>>(h0, sc, l1w1, l2w1, G);
  conv_kernel<<<4096, 256, 0, stream>>>(G, we1, colb, l1b1, l2b1,
                                        h1, bn + 16384, bn + 24576);
  bnfin_kernel<<<1, 32, 0, stream>>>(bn + 16384, bn + 24576, bng1, bnb1,
                                     sc + 64, sc + 96);
  fc1_kernel<<<1024, 256, 0, stream>>>(h1, sc + 64, fc1w, fc1acc);
  fc2_kernel<<<2, 256, 0, stream>>>(fc1acc, fc2w, fc2b, out);
}

// Round 2
// 346.508 us; speedup vs baseline: 1.1279x; 1.0752x over previous
//
#include <hip/hip_runtime.h>

#define B_ 8
#define M_ 4096
#define W_ 128
#define C_ 32
#define NN_ 16

typedef short s16x8 __attribute__((ext_vector_type(8)));
typedef float f32x4 __attribute__((ext_vector_type(4)));

static __device__ __forceinline__ unsigned short f2bf(float f) {
  unsigned u = __builtin_bit_cast(unsigned, f);
  u = u + 0x7FFFu + ((u >> 16) & 1u);   // RNE
  return (unsigned short)(u >> 16);
}
static __device__ __forceinline__ s16x8 cvt8v(float4 a, float4 b) {
  s16x8 r;
  r[0] = (short)f2bf(a.x); r[1] = (short)f2bf(a.y);
  r[2] = (short)f2bf(a.z); r[3] = (short)f2bf(a.w);
  r[4] = (short)f2bf(b.x); r[5] = (short)f2bf(b.y);
  r[6] = (short)f2bf(b.z); r[7] = (short)f2bf(b.w);
  return r;
}
static __device__ __forceinline__ float safeexp(float a) {
  return expf(fminf(a, 87.f));
}

// ---------------------------------------------------------------- poison (diagnostic sentinel)
__global__ void poison_kernel(float* __restrict__ out, int n, float val) {
  int t = blockIdx.x * blockDim.x + threadIdx.x;
  if (t < n) out[t] = val;
}

// ---------------------------------------------------------------- init: fc1acc = fc1b; bn slots = 0
__global__ __launch_bounds__(256) void init_kernel(
    float* __restrict__ fc1acc, const float* __restrict__ fc1b,
    float* __restrict__ bn) {
  int g = blockIdx.x * 256 + threadIdx.x;
  if (g < 2048) fc1acc[g] = fc1b[g & 255];
  else if (g < 34816) bn[g - 2048] = 0.f;
}

// ---------------------------------------------------------------- attention: one THREAD per row (proven)
__global__ __launch_bounds__(256) void attn_kernel(
    const float* __restrict__ pseudo, const int* __restrict__ Lidx,
    const float* __restrict__ edge_w, const float* __restrict__ edge_b,
    const float* __restrict__ mu0, const float* __restrict__ sg0,
    const float* __restrict__ mu1, const float* __restrict__ sg1,
    float* __restrict__ we0, float* __restrict__ we1, int* __restrict__ colb) {
  int m = blockIdx.x * 256 + threadIdx.x;
  if (m >= M_) return;
  float w0[NN_], w1[NN_];
  int col[NN_];
#pragma unroll
  for (int n = 0; n < NN_; n++) {
    int e = m * NN_ + n;
    float p0 = pseudo[e * 2], p1 = pseudo[e * 2 + 1];
    float emb[5];
#pragma unroll
    for (int d = 0; d < 5; d++)
      emb[d] = p0 * edge_w[d * 2] + p1 * edge_w[d * 2 + 1] + edge_b[d];
    float a0 = 0.f, a1 = 0.f;
#pragma unroll
    for (int j = 0; j < 4; j++) {
      float qa = 0.f, qb = 0.f;
#pragma unroll
      for (int d = 0; d < 5; d++) {
        float u0 = emb[d] - mu0[j * 5 + d];
        qa += u0 * u0 * sg0[j * 5 + d];
        float u1 = emb[d] - mu1[j * 5 + d];
        qb += u1 * u1 * sg1[j * 5 + d];
      }
      a0 += safeexp(-0.5f * qa);
      a1 += safeexp(-0.5f * qb);
    }
    w0[n] = a0; w1[n] = a1;
    col[n] = Lidx[e] % M_;
  }
  float mx0 = w0[0], mx1 = w1[0];
#pragma unroll
  for (int n = 1; n < NN_; n++) { mx0 = fmaxf(mx0, w0[n]); mx1 = fmaxf(mx1, w1[n]); }
  float s0 = 0.f, s1 = 0.f;
#pragma unroll
  for (int n = 0; n < NN_; n++) {
    w0[n] = safeexp(w0[n] - mx0); s0 += w0[n];
    w1[n] = safeexp(w1[n] - mx1); s1 += w1[n];
  }
  float r0 = 1.f / s0, r1 = 1.f / s1;
#pragma unroll
  for (int n = 0; n < NN_; n++) {
    bool last = true;                       // numpy fancy-set: last duplicate wins
#pragma unroll
    for (int n2 = n + 1; n2 < NN_; n2++)
      if (col[n2] == col[n]) last = false;
    int e = m * NN_ + n;
    we0[e] = last ? w0[n] * r0 : 0.f;
    we1[e] = last ? w1[n] * r1 : 0.f;
    colb[e] = col[n];
  }
}

// ---------------------------------------------------------------- proj0 (MFMA): G[r][0:32]=x@l1w0.T, G[r][32:64]=x@l2w0.T
__global__ __launch_bounds__(256) void proj0_kernel(
    const float* __restrict__ x, const float* __restrict__ l1w0,
    const float* __restrict__ l2w0, float* __restrict__ G) {
  int lane = threadIdx.x & 63, wave = threadIdx.x >> 6;
  int l16 = lane & 15, quad = lane >> 4;
  int tile = blockIdx.x * 4 + wave;            // 2048 tiles of 16 rows
  s16x8 bf[4][4];
#pragma unroll
  for (int kit = 0; kit < 4; kit++) {
#pragma unroll
    for (int ct = 0; ct < 4; ct++) {
      int out = ct * 16 + l16;                 // 0..63
      const float* src = (out < 32 ? l1w0 + out * 128 : l2w0 + (out - 32) * 128)
                         + kit * 32 + quad * 8;
      bf[kit][ct] = cvt8v(*(const float4*)src, *(const float4*)(src + 4));
    }
  }
  f32x4 acc[4];
#pragma unroll
  for (int ct = 0; ct < 4; ct++) acc[ct] = (f32x4){0.f, 0.f, 0.f, 0.f};
  int row = tile * 16 + l16;
  const float* xr = x + (size_t)row * 128 + quad * 8;
#pragma unroll
  for (int kit = 0; kit < 4; kit++) {
    const float* ap = xr + kit * 32;
    s16x8 a = cvt8v(*(const float4*)ap, *(const float4*)(ap + 4));
#pragma unroll
    for (int ct = 0; ct < 4; ct++)
      acc[ct] = __builtin_amdgcn_mfma_f32_16x16x32_bf16(a, bf[kit][ct], acc[ct], 0, 0, 0);
  }
  int rbase = tile * 16 + quad * 4;            // C/D: col=lane&15, row=quad*4+i (m89)
#pragma unroll
  for (int ct = 0; ct < 4; ct++)
#pragma unroll
    for (int i = 0; i < 4; i++)
      G[(size_t)(rbase + i) * 64 + ct * 16 + l16] = acc[ct][i];
}

// ---------------------------------------------------------------- conv (shared for both layers):
// h = L.G1 + G2 + b1 + b2; BN partials via LDS reduction.
// Block = 8 rows x 32 ch. Stage (we,col) in LDS -> 16 independent gathers in flight.
__global__ __launch_bounds__(256) void conv_kernel(
    const float* __restrict__ G,
    const float* __restrict__ we, const int* __restrict__ colb,
    const float* __restrict__ b1c, const float* __restrict__ b2c,
    float* __restrict__ h, float* __restrict__ bns, float* __restrict__ bnq) {
  __shared__ float s_we[8][16];
  __shared__ int   s_cn[8][16];
  __shared__ float s_s[32], s_q[32];
  int tid = threadIdx.x;
  if (tid < 128) {
    int row = tid >> 4, nn = tid & 15;
    int m = (blockIdx.x * 8 + row) & 4095;     // attn arrays are per-m (batch-independent)
    s_we[row][nn] = we[m * 16 + nn];
    s_cn[row][nn] = colb[m * 16 + nn];
  } else if (tid < 160) {
    s_s[tid - 128] = 0.f;
    s_q[tid - 128] = 0.f;
  }
  __syncthreads();
  int row = tid >> 5, c = tid & 31;
  int r = blockIdx.x * 8 + row;
  int b = r >> 12;
  const float* Gb = G + ((size_t)b << 18);     // b*4096*64
  float acc = 0.f;
#pragma unroll
  for (int nn = 0; nn < NN_; nn++)             // all 16 loads independent -> in flight together
    acc += s_we[row][nn] * Gb[s_cn[row][nn] * 64 + c];
  float hv = acc + G[(size_t)r * 64 + 32 + c] + b1c[c] + b2c[c];
  h[(size_t)r * 32 + c] = hv;
  atomicAdd(&s_s[c], hv);                      // LDS atomic (ds_add_f32), 8-way per addr
  atomicAdd(&s_q[c], hv * hv);
  __syncthreads();
  if (tid < 32) {
    int slot = blockIdx.x & 255;
    atomicAdd(&bns[tid * 256 + slot], s_s[tid]);
    atomicAdd(&bnq[tid * 256 + slot], s_q[tid]);
  }
}

// ---------------------------------------------------------------- BN finalize (parallel: 8 partials/channel)
__global__ __launch_bounds__(256) void bnfin_kernel(
    const float* __restrict__ bns, const float* __restrict__ bnq,
    const float* __restrict__ g, const float* __restrict__ bb,
    float* __restrict__ scale, float* __restrict__ shift) {
  __shared__ float red[2][8][32];
  int tid = threadIdx.x;
  int c = tid & 31, part = tid >> 5;           // 8 partial sums per channel
  float s = 0.f, q = 0.f;
#pragma unroll 8
  for (int i = 0; i < 32; i++) {
    s += bns[c * 256 + part * 32 + i];
    q += bnq[c * 256 + part * 32 + i];
  }
  red[0][part][c] = s;
  red[1][part][c] = q;
  __syncthreads();
  if (tid < 32) {
    float S = 0.f, Q = 0.f;
#pragma unroll
    for (int p = 0; p < 8; p++) { S += red[0][p][tid]; Q += red[1][p][tid]; }
    float mean = S * (1.f / 32768.f);
    float var = fmaxf(Q * (1.f / 32768.f) - mean * mean, 0.f);
    float sc = g[tid] * rsqrtf(var + 1e-5f);
    scale[tid] = sc;
    shift[tid] = bb[tid] - mean * sc;
  }
}

// ---------------------------------------------------------------- proj1 (MFMA, K=32): a=relu(bn0(h0)); G=[a@l1w1.T | a@l2w1.T]
__global__ __launch_bounds__(256) void proj1_kernel(
    const float* __restrict__ h0, const float* __restrict__ sc0,
    const float* __restrict__ l1w1, const float* __restrict__ l2w1,
    float* __restrict__ G) {
  int lane = threadIdx.x & 63, wave = threadIdx.x >> 6;
  int l16 = lane & 15, quad = lane >> 4;
  int tile = blockIdx.x * 4 + wave;
  s16x8 bf[4];
#pragma unroll
  for (int ct = 0; ct < 4; ct++) {
    int out = ct * 16 + l16;
    const float* src = (out < 32 ? l1w1 + out * 32 : l2w1 + (out - 32) * 32) + quad * 8;
    bf[ct] = cvt8v(*(const float4*)src, *(const float4*)(src + 4));
  }
  float scv[8], shv[8];
#pragma unroll
  for (int j = 0; j < 8; j++) {
    scv[j] = sc0[quad * 8 + j];
    shv[j] = sc0[32 + quad * 8 + j];
  }
  int row = tile * 16 + l16;
  const float* hr = h0 + (size_t)row * 32 + quad * 8;
  float4 hv0 = *(const float4*)hr;
  float4 hv1 = *(const float4*)(hr + 4);
  float av[8] = {hv0.x, hv0.y, hv0.z, hv0.w, hv1.x, hv1.y, hv1.z, hv1.w};
  s16x8 a;
#pragma unroll
  for (int j = 0; j < 8; j++)
    a[j] = (short)f2bf(fmaxf(av[j] * scv[j] + shv[j], 0.f));
  f32x4 acc[4];
#pragma unroll
  for (int ct = 0; ct < 4; ct++) {
    f32x4 z = {0.f, 0.f, 0.f, 0.f};
    acc[ct] = __builtin_amdgcn_mfma_f32_16x16x32_bf16(a, bf[ct], z, 0, 0, 0);
  }
  int rbase = tile * 16 + quad * 4;
#pragma unroll
  for (int ct = 0; ct < 4; ct++)
#pragma unroll
    for (int i = 0; i < 4; i++)
      G[(size_t)(rbase + i) * 64 + ct * 16 + l16] = acc[ct][i];
}

// ---------------------------------------------------------------- fc1 (MFMA rewrite):
// out[16 x 256] = A[16 x 131072] @ fc1w.T, batches in rows 0..7 (8..15 zero).
// Grid = 128 k-chunks x 4 o-groups. Block: stage A-chunk [16][1024] bf16 in LDS
// (bn+relu applied, XOR-swizzled rows); each of 4 waves owns 16 outputs,
// K-loops 32 MFMAs with ONE f32x4 accumulator -> ~40 live VGPRs, no spills
// (old VALU version needed acc[8][8]=64 floats -> 47-68 MB scratch traffic).
__global__ __launch_bounds__(256) void fc1_kernel(
    const float* __restrict__ h1, const float* __restrict__ sc1,
    const float* __restrict__ fc1w, float* __restrict__ fc1acc) {
  __shared__ short als[16 * 1024];             // bf16 [row][k], row stride 2048 B, swizzled
  int tid = threadIdx.x;
  int kc = blockIdx.x >> 2;                    // 0..127: k-chunk of 1024
  int og = blockIdx.x & 3;                     // 0..3: outputs og*64..+63
  size_t kbase = (size_t)kc << 10;
  // stage: 4096 short4-slots (rows 0..7 = relu(bn(h1)), rows 8..15 = zero)
  for (int s = tid; s < 4096; s += 256) {
    int rowb = s >> 8;                         // 0..15
    int k4 = (s & 255) << 2;                   // 0..1020 step 4
    short4 v4 = {0, 0, 0, 0};
    if (rowb < 8) {
      float4 hv = *(const float4*)(h1 + ((size_t)rowb << 17) + kbase + k4);
      int c = k4 & 31;
      float4 scv = *(const float4*)(sc1 + c);
      float4 shv = *(const float4*)(sc1 + 32 + c);
      v4.x = (short)f2bf(fmaxf(hv.x * scv.x + shv.x, 0.f));
      v4.y = (short)f2bf(fmaxf(hv.y * scv.y + shv.y, 0.f));
      v4.z = (short)f2bf(fmaxf(hv.z * scv.z + shv.z, 0.f));
      v4.w = (short)f2bf(fmaxf(hv.w * scv.w + shv.w, 0.f));
    }
    int byte = ((rowb << 11) + (k4 << 1)) ^ ((rowb & 7) << 4);  // G4 swizzle
    *(short4*)((char*)als + byte) = v4;
  }
  __syncthreads();
  int lane = tid & 63, wave = tid >> 6;
  int l16 = lane & 15, quad = lane >> 4;
  const float* wrow = fc1w + (size_t)(og * 64 + wave * 16 + l16) * 131072
                      + kbase + quad * 8;
  int abase = (l16 << 11) + (quad << 4);       // byte offset pre-swizzle
  int axor = (l16 & 7) << 4;
  f32x4 acc = {0.f, 0.f, 0.f, 0.f};
#pragma unroll 4
  for (int kk = 0; kk < 32; kk++) {
    const float* wp = wrow + kk * 32;
    s16x8 bfr = cvt8v(*(const float4*)wp, *(const float4*)(wp + 4));
    s16x8 afr = *(const s16x8*)((const char*)als + ((abase + (kk << 6)) ^ axor));
    acc = __builtin_amdgcn_mfma_f32_16x16x32_bf16(afr, bfr, acc, 0, 0, 0);
  }
  if (quad < 2) {                              // D rows 0..7 = batches (m89 layout)
    int o = og * 64 + wave * 16 + l16;
#pragma unroll
    for (int i = 0; i < 4; i++)
      atomicAdd(&fc1acc[(quad * 4 + i) * 256 + o], acc[i]);
  }
}

// ---------------------------------------------------------------- fc2 -> fp32 out
__global__ void fc2_kernel(const float* __restrict__ fc1acc,
                           const float* __restrict__ fc2w,
                           const float* __restrict__ fc2b,
                           float* __restrict__ out) {
  int t = blockIdx.x * blockDim.x + threadIdx.x;
  if (t >= 424) return;
  int b = t / 53, j = t - b * 53;
  float s = fc2b[j];
  const float* fa = fc1acc + b * 256;
  const float* wr = fc2w + j * 256;
#pragma unroll 8
  for (int o = 0; o < 256; o++) s += fmaxf(fa[o], 0.f) * wr[o];
  out[t] = s;
}

// ---------------------------------------------------------------- launch
extern "C" void kernel_launch(void* const* d_in, const int* in_sizes, int n_in,
                              void* d_out, int out_size, void* d_ws, size_t ws_size,
                              hipStream_t stream) {
  float* out = (float*)d_out;
  int bad = 0;
  if (n_in != 25) bad = 2;
  else if (in_sizes[0] != 4194304) bad = 3;
  else if (in_sizes[2] != 65536) bad = 4;
  else if (in_sizes[21] != 33554432) bad = 5;
  else if (out_size != 424) bad = 6;
  else if (ws_size < 13509120) bad = 1;
  if (bad) {
    poison_kernel<<<2, 256, 0, stream>>>(out, out_size, (float)bad * 1.0e6f);
    return;
  }

  const float* x      = (const float*)d_in[0];
  const float* pseudo = (const float*)d_in[1];
  const int*   Lidx   = (const int*)d_in[2];
  const float* edge_w = (const float*)d_in[3];
  const float* edge_b = (const float*)d_in[4];
  const float* mu0    = (const float*)d_in[5];
  const float* sg0    = (const float*)d_in[6];
  const float* mu1    = (const float*)d_in[7];
  const float* sg1    = (const float*)d_in[8];
  const float* l1w0   = (const float*)d_in[9];
  const float* l1b0   = (const float*)d_in[10];
  const float* l2w0   = (const float*)d_in[11];
  const float* l2b0   = (const float*)d_in[12];
  const float* l1w1   = (const float*)d_in[13];
  const float* l1b1   = (const float*)d_in[14];
  const float* l2w1   = (const float*)d_in[15];
  const float* l2b1   = (const float*)d_in[16];
  const float* bng0   = (const float*)d_in[17];
  const float* bnb0   = (const float*)d_in[18];
  const float* bng1   = (const float*)d_in[19];
  const float* bnb1   = (const float*)d_in[20];
  const float* fc1w   = (const float*)d_in[21];
  const float* fc1b   = (const float*)d_in[22];
  const float* fc2w   = (const float*)d_in[23];
  const float* fc2b   = (const float*)d_in[24];

  char* Wp = (char*)d_ws;
  int*   colb   = (int*)  (Wp + 0);          // 65536 i32
  float* we0    = (float*)(Wp + 262144);     // 65536 f32
  float* we1    = (float*)(Wp + 524288);     // 65536 f32
  float* G      = (float*)(Wp + 786432);     // 32768 x 64 f32 (8 MB): [.,0:32]=G1, [.,32:64]=G2
  float* h0     = (float*)(Wp + 9175040);    // 32768 x 32 f32 (4 MB)
  float* h1     = (float*)(Wp + 9175040);    // aliases h0 (h0 dead after proj1)
  float* bn     = (float*)(Wp + 13369344);   // 4 x (32ch x 256 slots) f32
  float* sc     = (float*)(Wp + 13500416);   // scale0,shift0,scale1,shift1
  float* fc1acc = (float*)(Wp + 13500928);   // 8x256 f32

  init_kernel<<<136, 256, 0, stream>>>(fc1acc, fc1b, bn);
  attn_kernel<<<16, 256, 0, stream>>>(pseudo, Lidx, edge_w, edge_b,
                                      mu0, sg0, mu1, sg1, we0, we1, colb);
  proj0_kernel<<<512, 256, 0, stream>>>(x, l1w0, l2w0, G);
  conv_kernel<<<4096, 256, 0, stream>>>(G, we0, colb, l1b0, l2b0,
                                        h0, bn, bn + 8192);
  bnfin_kernel<<<1, 256, 0, stream>>>(bn, bn + 8192, bng0, bnb0, sc, sc + 32);
  proj1_kernel<<<512, 256, 0, stream>>>(h0, sc, l1w1, l2w1, G);
  conv_kernel<<<4096, 256, 0, stream>>>(G, we1, colb, l1b1, l2b1,
                                        h1, bn + 16384, bn + 24576);
  bnfin_kernel<<<1, 256, 0, stream>>>(bn + 16384, bn + 24576, bng1, bnb1,
                                      sc + 64, sc + 96);
  fc1_kernel<<<512, 256, 0, stream>>>(h1, sc + 64, fc1w, fc1acc);
  fc2_kernel<<<2, 256, 0, stream>>>(fc1acc, fc2w, fc2b, out);
}

// Round 3
// 340.637 us; speedup vs baseline: 1.1473x; 1.0172x over previous
//
#include <hip/hip_runtime.h>
#include <hip/hip_cooperative_groups.h>

namespace cg = cooperative_groups;

#define B_ 8
#define M_ 4096
#define W_ 128
#define C_ 32
#define NN_ 16

typedef short s16x8 __attribute__((ext_vector_type(8)));
typedef float f32x4 __attribute__((ext_vector_type(4)));

static __device__ __forceinline__ unsigned short f2bf(float f) {
  unsigned u = __builtin_bit_cast(unsigned, f);
  u = u + 0x7FFFu + ((u >> 16) & 1u);   // RNE
  return (unsigned short)(u >> 16);
}
static __device__ __forceinline__ s16x8 cvt8v(float4 a, float4 b) {
  s16x8 r;
  r[0] = (short)f2bf(a.x); r[1] = (short)f2bf(a.y);
  r[2] = (short)f2bf(a.z); r[3] = (short)f2bf(a.w);
  r[4] = (short)f2bf(b.x); r[5] = (short)f2bf(b.y);
  r[6] = (short)f2bf(b.z); r[7] = (short)f2bf(b.w);
  return r;
}
static __device__ __forceinline__ float safeexp(float a) {
  return expf(fminf(a, 87.f));
}

// ---------------------------------------------------------------- poison (diagnostic sentinel)
__global__ void poison_kernel(float* __restrict__ out, int n, float val) {
  int t = blockIdx.x * blockDim.x + threadIdx.x;
  if (t < n) out[t] = val;
}

// ================================================================ device bodies (shared by
// the cooperative fused kernel and the standalone fallback kernels)

// ---- attention row (proven)
static __device__ void attn_row(
    int m, const float* __restrict__ pseudo, const int* __restrict__ Lidx,
    const float* __restrict__ edge_w, const float* __restrict__ edge_b,
    const float* __restrict__ mu0, const float* __restrict__ sg0,
    const float* __restrict__ mu1, const float* __restrict__ sg1,
    float* __restrict__ we0, float* __restrict__ we1, int* __restrict__ colb) {
  float w0[NN_], w1[NN_];
  int col[NN_];
#pragma unroll
  for (int n = 0; n < NN_; n++) {
    int e = m * NN_ + n;
    float p0 = pseudo[e * 2], p1 = pseudo[e * 2 + 1];
    float emb[5];
#pragma unroll
    for (int d = 0; d < 5; d++)
      emb[d] = p0 * edge_w[d * 2] + p1 * edge_w[d * 2 + 1] + edge_b[d];
    float a0 = 0.f, a1 = 0.f;
#pragma unroll
    for (int j = 0; j < 4; j++) {
      float qa = 0.f, qb = 0.f;
#pragma unroll
      for (int d = 0; d < 5; d++) {
        float u0 = emb[d] - mu0[j * 5 + d];
        qa += u0 * u0 * sg0[j * 5 + d];
        float u1 = emb[d] - mu1[j * 5 + d];
        qb += u1 * u1 * sg1[j * 5 + d];
      }
      a0 += safeexp(-0.5f * qa);
      a1 += safeexp(-0.5f * qb);
    }
    w0[n] = a0; w1[n] = a1;
    col[n] = Lidx[e] % M_;
  }
  float mx0 = w0[0], mx1 = w1[0];
#pragma unroll
  for (int n = 1; n < NN_; n++) { mx0 = fmaxf(mx0, w0[n]); mx1 = fmaxf(mx1, w1[n]); }
  float s0 = 0.f, s1 = 0.f;
#pragma unroll
  for (int n = 0; n < NN_; n++) {
    w0[n] = safeexp(w0[n] - mx0); s0 += w0[n];
    w1[n] = safeexp(w1[n] - mx1); s1 += w1[n];
  }
  float r0 = 1.f / s0, r1 = 1.f / s1;
#pragma unroll
  for (int n = 0; n < NN_; n++) {
    bool last = true;                       // numpy fancy-set: last duplicate wins
#pragma unroll
    for (int n2 = n + 1; n2 < NN_; n2++)
      if (col[n2] == col[n]) last = false;
    int e = m * NN_ + n;
    we0[e] = last ? w0[n] * r0 : 0.f;
    we1[e] = last ? w1[n] * r1 : 0.f;
    colb[e] = col[n];
  }
}

// ---- proj0 tile: G[r][0:32]=x@l1w0.T, G[r][32:64]=x@l2w0.T
// (bf fragments loaded per-kit to keep live VGPRs < 128 for the coop launch)
static __device__ void proj0_tile(
    int blk, int tid, const float* __restrict__ x, const float* __restrict__ l1w0,
    const float* __restrict__ l2w0, float* __restrict__ G) {
  int lane = tid & 63, wave = tid >> 6;
  int l16 = lane & 15, quad = lane >> 4;
  int tile = blk * 4 + wave;                   // 2048 tiles of 16 rows
  f32x4 acc[4];
#pragma unroll
  for (int ct = 0; ct < 4; ct++) acc[ct] = (f32x4){0.f, 0.f, 0.f, 0.f};
  int row = tile * 16 + l16;
  const float* xr = x + (size_t)row * 128 + quad * 8;
  int out0 = l16;                              // per-ct: out = ct*16+l16
#pragma unroll
  for (int kit = 0; kit < 4; kit++) {
    const float* ap = xr + kit * 32;
    s16x8 a = cvt8v(*(const float4*)ap, *(const float4*)(ap + 4));
#pragma unroll
    for (int ct = 0; ct < 4; ct++) {
      int out = ct * 16 + out0;
      const float* src = (out < 32 ? l1w0 + out * 128 : l2w0 + (out - 32) * 128)
                         + kit * 32 + quad * 8;
      s16x8 bf = cvt8v(*(const float4*)src, *(const float4*)(src + 4));
      acc[ct] = __builtin_amdgcn_mfma_f32_16x16x32_bf16(a, bf, acc[ct], 0, 0, 0);
    }
  }
  int rbase = tile * 16 + quad * 4;            // C/D: col=lane&15, row=quad*4+i (m89)
#pragma unroll
  for (int ct = 0; ct < 4; ct++)
#pragma unroll
    for (int i = 0; i < 4; i++)
      G[(size_t)(rbase + i) * 64 + ct * 16 + l16] = acc[ct][i];
}

// ---- conv block (proven): h = L.G1 + G2 + b1 + b2; BN partials. smem needs 1280 B.
static __device__ void conv_block(
    int cb, int tid, char* smem,
    const float* __restrict__ G, const float* __restrict__ we,
    const int* __restrict__ colb, const float* __restrict__ b1c,
    const float* __restrict__ b2c, float* __restrict__ h,
    float* __restrict__ bns, float* __restrict__ bnq) {
  float (*s_we)[16] = (float(*)[16])smem;
  int   (*s_cn)[16] = (int(*)[16])(smem + 512);
  float* s_s = (float*)(smem + 1024);
  float* s_q = (float*)(smem + 1152);
  if (tid < 128) {
    int row = tid >> 4, nn = tid & 15;
    int m = (cb * 8 + row) & 4095;             // attn arrays are per-m
    s_we[row][nn] = we[m * 16 + nn];
    s_cn[row][nn] = colb[m * 16 + nn];
  } else if (tid < 160) {
    s_s[tid - 128] = 0.f;
    s_q[tid - 128] = 0.f;
  }
  __syncthreads();
  int row = tid >> 5, c = tid & 31;
  int r = cb * 8 + row;
  int b = r >> 12;
  const float* Gb = G + ((size_t)b << 18);     // b*4096*64
  float acc = 0.f;
#pragma unroll
  for (int nn = 0; nn < NN_; nn++)             // 16 independent gathers in flight
    acc += s_we[row][nn] * Gb[s_cn[row][nn] * 64 + c];
  float hv = acc + G[(size_t)r * 64 + 32 + c] + b1c[c] + b2c[c];
  h[(size_t)r * 32 + c] = hv;
  atomicAdd(&s_s[c], hv);
  atomicAdd(&s_q[c], hv * hv);
  __syncthreads();
  if (tid < 32) {
    int slot = cb & 255;
    atomicAdd(&bns[tid * 256 + slot], s_s[tid]);
    atomicAdd(&bnq[tid * 256 + slot], s_q[tid]);
  }
}

// ---- BN finalize (parallel, 256 threads). smem needs 2048 B.
static __device__ void bnfin_block(
    int tid, char* smem, const float* __restrict__ bns, const float* __restrict__ bnq,
    const float* __restrict__ g, const float* __restrict__ bb,
    float* __restrict__ scale, float* __restrict__ shift) {
  float (*red)[8][32] = (float(*)[8][32])smem;
  int c = tid & 31, part = tid >> 5;
  float s = 0.f, q = 0.f;
#pragma unroll 8
  for (int i = 0; i < 32; i++) {
    s += bns[c * 256 + part * 32 + i];
    q += bnq[c * 256 + part * 32 + i];
  }
  red[0][part][c] = s;
  red[1][part][c] = q;
  __syncthreads();
  if (tid < 32) {
    float S = 0.f, Q = 0.f;
#pragma unroll
    for (int p = 0; p < 8; p++) { S += red[0][p][tid]; Q += red[1][p][tid]; }
    float mean = S * (1.f / 32768.f);
    float var = fmaxf(Q * (1.f / 32768.f) - mean * mean, 0.f);
    float sc = g[tid] * rsqrtf(var + 1e-5f);
    scale[tid] = sc;
    shift[tid] = bb[tid] - mean * sc;
  }
}

// ---- proj1 tile (K=32): a=relu(bn0(h0)); G=[a@l1w1.T | a@l2w1.T]
static __device__ void proj1_tile(
    int blk, int tid, const float* __restrict__ h0, const float* __restrict__ sc0,
    const float* __restrict__ l1w1, const float* __restrict__ l2w1,
    float* __restrict__ G) {
  int lane = tid & 63, wave = tid >> 6;
  int l16 = lane & 15, quad = lane >> 4;
  int tile = blk * 4 + wave;
  int row = tile * 16 + l16;
  const float* hr = h0 + (size_t)row * 32 + quad * 8;
  float4 hv0 = *(const float4*)hr;
  float4 hv1 = *(const float4*)(hr + 4);
  float av[8] = {hv0.x, hv0.y, hv0.z, hv0.w, hv1.x, hv1.y, hv1.z, hv1.w};
  s16x8 a;
#pragma unroll
  for (int j = 0; j < 8; j++) {
    float scv = sc0[quad * 8 + j];
    float shv = sc0[32 + quad * 8 + j];
    a[j] = (short)f2bf(fmaxf(av[j] * scv + shv, 0.f));
  }
  f32x4 acc[4];
#pragma unroll
  for (int ct = 0; ct < 4; ct++) {
    int out = ct * 16 + l16;
    const float* src = (out < 32 ? l1w1 + out * 32 : l2w1 + (out - 32) * 32) + quad * 8;
    s16x8 bf = cvt8v(*(const float4*)src, *(const float4*)(src + 4));
    f32x4 z = {0.f, 0.f, 0.f, 0.f};
    acc[ct] = __builtin_amdgcn_mfma_f32_16x16x32_bf16(a, bf, z, 0, 0, 0);
  }
  int rbase = tile * 16 + quad * 4;
#pragma unroll
  for (int ct = 0; ct < 4; ct++)
#pragma unroll
    for (int i = 0; i < 4; i++)
      G[(size_t)(rbase + i) * 64 + ct * 16 + l16] = acc[ct][i];
}

// ---- fc1 block (MFMA, K-chunk=512 -> 16 KB LDS): u = kc*4+og, u in [0,1024)
static __device__ void fc1_block(
    int u, int tid, char* smem, const float* __restrict__ h1,
    const float* __restrict__ sc1, const float* __restrict__ fc1w,
    float* __restrict__ fc1acc) {
  short* als = (short*)smem;                   // bf16 [16][512], row stride 1024 B, swizzled
  int kc = u >> 2;                             // 0..255: k-chunk of 512
  int og = u & 3;                              // 0..3: outputs og*64..+63
  size_t kbase = (size_t)kc << 9;
  for (int s = tid; s < 2048; s += 256) {      // 2048 short4 slots
    int rowb = s >> 7;                         // 0..15 (rows 8..15 stay zero)
    int k4 = (s & 127) << 2;
    short4 v4 = {0, 0, 0, 0};
    if (rowb < 8) {
      float4 hv = *(const float4*)(h1 + ((size_t)rowb << 17) + kbase + k4);
      int c = k4 & 31;
      float4 scv = *(const float4*)(sc1 + c);
      float4 shv = *(const float4*)(sc1 + 32 + c);
      v4.x = (short)f2bf(fmaxf(hv.x * scv.x + shv.x, 0.f));
      v4.y = (short)f2bf(fmaxf(hv.y * scv.y + shv.y, 0.f));
      v4.z = (short)f2bf(fmaxf(hv.z * scv.z + shv.z, 0.f));
      v4.w = (short)f2bf(fmaxf(hv.w * scv.w + shv.w, 0.f));
    }
    int byte = ((rowb << 10) + (k4 << 1)) ^ ((rowb & 7) << 4);  // G4 swizzle
    *(short4*)((char*)als + byte) = v4;
  }
  __syncthreads();
  int lane = tid & 63, wave = tid >> 6;
  int l16 = lane & 15, quad = lane >> 4;
  int o = og * 64 + wave * 16 + l16;
  const float* wr = fc1w + (size_t)o * 131072 + kbase + quad * 8;
  int abase = (l16 << 10) + (quad << 4);
  int axor = (l16 & 7) << 4;
  f32x4 acc = {0.f, 0.f, 0.f, 0.f};
#pragma unroll 4
  for (int kk = 0; kk < 16; kk++) {
    const float* wp = wr + kk * 32;
    s16x8 bfr = cvt8v(*(const float4*)wp, *(const float4*)(wp + 4));
    s16x8 afr = *(const s16x8*)((const char*)als + ((abase + (kk << 6)) ^ axor));
    acc = __builtin_amdgcn_mfma_f32_16x16x32_bf16(afr, bfr, acc, 0, 0, 0);
  }
  if (quad < 2) {                              // D rows 0..7 = batches (m89 layout)
#pragma unroll
    for (int i = 0; i < 4; i++)
      atomicAdd(&fc1acc[(quad * 4 + i) * 256 + o], acc[i]);
  }
  __syncthreads();
}

// ---- fc2 element
static __device__ void fc2_elem(
    int t, const float* __restrict__ fc1acc, const float* __restrict__ fc2w,
    const float* __restrict__ fc2b, float* __restrict__ out) {
  int b = t / 53, j = t - b * 53;
  float s = fc2b[j];
  const float* fa = fc1acc + b * 256;
  const float* wr = fc2w + j * 256;
#pragma unroll 8
  for (int o = 0; o < 256; o++) s += fmaxf(fa[o], 0.f) * wr[o];
  out[t] = s;
}

// ---- L3-warm: dead-read a quarter of fc1w; asm keeps loads live (rule #17)
static __device__ __forceinline__ void prefetch_q(
    const float* __restrict__ fc1w, int quarter, int idx, int stride) {
  const float4* p = (const float4*)fc1w + (size_t)quarter * 2097152;
  float acc = 0.f;
  for (int i = idx; i < 2097152; i += stride) {
    float4 v = p[i];
    acc += v.x + v.y + v.z + v.w;
  }
  asm volatile("" :: "v"(acc));
}

// ================================================================ cooperative fused kernel
// grid = 1024 x 256 (exactly 4 blocks/CU: VGPR<=128 via launch_bounds, 16 KB LDS).
// grid.sync() replaces 9 kernel boundaries; idle blocks warm fc1w into L3 so the
// fc1 phase reads 134 MB at L3 speed instead of HBM.
__global__ __launch_bounds__(256, 4) void fused_kernel(
    const float* __restrict__ x, const float* __restrict__ pseudo,
    const int* __restrict__ Lidx,
    const float* __restrict__ edge_w, const float* __restrict__ edge_b,
    const float* __restrict__ mu0, const float* __restrict__ sg0,
    const float* __restrict__ mu1, const float* __restrict__ sg1,
    const float* __restrict__ l1w0, const float* __restrict__ l1b0,
    const float* __restrict__ l2w0, const float* __restrict__ l2b0,
    const float* __restrict__ l1w1, const float* __restrict__ l1b1,
    const float* __restrict__ l2w1, const float* __restrict__ l2b1,
    const float* __restrict__ bng0, const float* __restrict__ bnb0,
    const float* __restrict__ bng1, const float* __restrict__ bnb1,
    const float* __restrict__ fc1w, const float* __restrict__ fc1b,
    const float* __restrict__ fc2w, const float* __restrict__ fc2b,
    float* __restrict__ out,
    int* __restrict__ colb, float* __restrict__ we0, float* __restrict__ we1,
    float* __restrict__ G, float* __restrict__ h,
    float* __restrict__ bn, float* __restrict__ sc, float* __restrict__ fc1acc) {
  __shared__ char smem[16384];
  cg::grid_group grid = cg::this_grid();
  int bid = blockIdx.x, tid = threadIdx.x;
  int gtid = bid * 256 + tid;

  // ---- P0: init + attention
  if (gtid < 2048) fc1acc[gtid] = fc1b[gtid & 255];
  else if (gtid < 34816) bn[gtid - 2048] = 0.f;
  if (bid < 16)
    attn_row(gtid, pseudo, Lidx, edge_w, edge_b, mu0, sg0, mu1, sg1, we0, we1, colb);
  grid.sync();

  // ---- P1: proj0 (blocks 0..511) || prefetch Q0 (blocks 512..1023)
  if (bid < 512) proj0_tile(bid, tid, x, l1w0, l2w0, G);
  else           prefetch_q(fc1w, 0, (bid - 512) * 256 + tid, 131072);
  grid.sync();

  // ---- P2: conv0 (4 iters) + prefetch Q1 (all blocks, after conv work)
  for (int it = 0; it < 4; it++) {
    __syncthreads();
    conv_block(bid + it * 1024, tid, smem, G, we0, colb, l1b0, l2b0,
               h, bn, bn + 8192);
  }
  prefetch_q(fc1w, 1, gtid, 262144);
  grid.sync();

  // ---- P3: bnfin0 (block 0) || prefetch Q2
  if (bid == 0) bnfin_block(tid, smem, bn, bn + 8192, bng0, bnb0, sc, sc + 32);
  else          prefetch_q(fc1w, 2, gtid - 256, 261888);
  grid.sync();

  // ---- P4: proj1 (blocks 0..511) || prefetch Q3
  if (bid < 512) proj1_tile(bid, tid, h, sc, l1w1, l2w1, G);
  else           prefetch_q(fc1w, 3, (bid - 512) * 256 + tid, 131072);
  grid.sync();

  // ---- P5: conv1 (4 iters)
  for (int it = 0; it < 4; it++) {
    __syncthreads();
    conv_block(bid + it * 1024, tid, smem, G, we1, colb, l1b1, l2b1,
               h, bn + 16384, bn + 24576);
  }
  grid.sync();

  // ---- P6: bnfin1 (block 0)
  if (bid == 0) bnfin_block(tid, smem, bn + 16384, bn + 24576, bng1, bnb1,
                            sc + 64, sc + 96);
  grid.sync();

  // ---- P7: fc1 (all 1024 blocks; weights L3-hot)
  fc1_block(bid, tid, smem, h, sc + 64, fc1w, fc1acc);
  grid.sync();

  // ---- P8: fc2
  if (gtid < 424) fc2_elem(gtid, fc1acc, fc2w, fc2b, out);
}

// ================================================================ standalone fallback kernels
__global__ __launch_bounds__(256) void init_kernel(
    float* __restrict__ fc1acc, const float* __restrict__ fc1b,
    float* __restrict__ bn) {
  int g = blockIdx.x * 256 + threadIdx.x;
  if (g < 2048) fc1acc[g] = fc1b[g & 255];
  else if (g < 34816) bn[g - 2048] = 0.f;
}

__global__ __launch_bounds__(256) void attn_kernel(
    const float* __restrict__ pseudo, const int* __restrict__ Lidx,
    const float* __restrict__ edge_w, const float* __restrict__ edge_b,
    const float* __restrict__ mu0, const float* __restrict__ sg0,
    const float* __restrict__ mu1, const float* __restrict__ sg1,
    float* __restrict__ we0, float* __restrict__ we1, int* __restrict__ colb) {
  int m = blockIdx.x * 256 + threadIdx.x;
  if (m < M_)
    attn_row(m, pseudo, Lidx, edge_w, edge_b, mu0, sg0, mu1, sg1, we0, we1, colb);
}

__global__ __launch_bounds__(256) void proj0_kernel(
    const float* __restrict__ x, const float* __restrict__ l1w0,
    const float* __restrict__ l2w0, float* __restrict__ G) {
  proj0_tile(blockIdx.x, threadIdx.x, x, l1w0, l2w0, G);
}

__global__ __launch_bounds__(256) void conv_kernel(
    const float* __restrict__ G,
    const float* __restrict__ we, const int* __restrict__ colb,
    const float* __restrict__ b1c, const float* __restrict__ b2c,
    float* __restrict__ h, float* __restrict__ bns, float* __restrict__ bnq) {
  __shared__ char smem[1280];
  conv_block(blockIdx.x, threadIdx.x, smem, G, we, colb, b1c, b2c, h, bns, bnq);
}

__global__ __launch_bounds__(256) void bnfin_kernel(
    const float* __restrict__ bns, const float* __restrict__ bnq,
    const float* __restrict__ g, const float* __restrict__ bb,
    float* __restrict__ scale, float* __restrict__ shift) {
  __shared__ char smem[2048];
  bnfin_block(threadIdx.x, smem, bns, bnq, g, bb, scale, shift);
}

__global__ __launch_bounds__(256) void proj1_kernel(
    const float* __restrict__ h0, const float* __restrict__ sc0,
    const float* __restrict__ l1w1, const float* __restrict__ l2w1,
    float* __restrict__ G) {
  proj1_tile(blockIdx.x, threadIdx.x, h0, sc0, l1w1, l2w1, G);
}

__global__ __launch_bounds__(256) void fc1_kernel(
    const float* __restrict__ h1, const float* __restrict__ sc1,
    const float* __restrict__ fc1w, float* __restrict__ fc1acc) {
  __shared__ char smem[16384];
  fc1_block(blockIdx.x, threadIdx.x, smem, h1, sc1, fc1w, fc1acc);
}

__global__ void fc2_kernel(const float* __restrict__ fc1acc,
                           const float* __restrict__ fc2w,
                           const float* __restrict__ fc2b,
                           float* __restrict__ out) {
  int t = blockIdx.x * blockDim.x + threadIdx.x;
  if (t < 424) fc2_elem(t, fc1acc, fc2w, fc2b, out);
}

// ---------------------------------------------------------------- launch
extern "C" void kernel_launch(void* const* d_in, const int* in_sizes, int n_in,
                              void* d_out, int out_size, void* d_ws, size_t ws_size,
                              hipStream_t stream) {
  float* out = (float*)d_out;
  int bad = 0;
  if (n_in != 25) bad = 2;
  else if (in_sizes[0] != 4194304) bad = 3;
  else if (in_sizes[2] != 65536) bad = 4;
  else if (in_sizes[21] != 33554432) bad = 5;
  else if (out_size != 424) bad = 6;
  else if (ws_size < 13509120) bad = 1;
  if (bad) {
    poison_kernel<<<2, 256, 0, stream>>>(out, out_size, (float)bad * 1.0e6f);
    return;
  }

  const float* x      = (const float*)d_in[0];
  const float* pseudo = (const float*)d_in[1];
  const int*   Lidx   = (const int*)d_in[2];
  const float* edge_w = (const float*)d_in[3];
  const float* edge_b = (const float*)d_in[4];
  const float* mu0    = (const float*)d_in[5];
  const float* sg0    = (const float*)d_in[6];
  const float* mu1    = (const float*)d_in[7];
  const float* sg1    = (const float*)d_in[8];
  const float* l1w0   = (const float*)d_in[9];
  const float* l1b0   = (const float*)d_in[10];
  const float* l2w0   = (const float*)d_in[11];
  const float* l2b0   = (const float*)d_in[12];
  const float* l1w1   = (const float*)d_in[13];
  const float* l1b1   = (const float*)d_in[14];
  const float* l2w1   = (const float*)d_in[15];
  const float* l2b1   = (const float*)d_in[16];
  const float* bng0   = (const float*)d_in[17];
  const float* bnb0   = (const float*)d_in[18];
  const float* bng1   = (const float*)d_in[19];
  const float* bnb1   = (const float*)d_in[20];
  const float* fc1w   = (const float*)d_in[21];
  const float* fc1b   = (const float*)d_in[22];
  const float* fc2w   = (const float*)d_in[23];
  const float* fc2b   = (const float*)d_in[24];

  char* Wp = (char*)d_ws;
  int*   colb   = (int*)  (Wp + 0);          // 65536 i32
  float* we0    = (float*)(Wp + 262144);     // 65536 f32
  float* we1    = (float*)(Wp + 524288);     // 65536 f32
  float* G      = (float*)(Wp + 786432);     // 32768 x 64 f32 (8 MB)
  float* h0     = (float*)(Wp + 9175040);    // 32768 x 32 f32 (4 MB); h1 aliases
  float* bn     = (float*)(Wp + 13369344);   // 4 x (32ch x 256 slots) f32
  float* sc     = (float*)(Wp + 13500416);   // scale0,shift0,scale1,shift1
  float* fc1acc = (float*)(Wp + 13500928);   // 8x256 f32

  // cooperative path: requires 4 blocks/CU co-residency for 1024 blocks
  int maxb = 0;
  hipError_t oe = hipOccupancyMaxActiveBlocksPerMultiprocessor(&maxb, fused_kernel, 256, 0);
  bool coop = (oe == hipSuccess && maxb >= 4);
  if (coop) {
    void* args[] = {
      (void*)&x, (void*)&pseudo, (void*)&Lidx, (void*)&edge_w, (void*)&edge_b,
      (void*)&mu0, (void*)&sg0, (void*)&mu1, (void*)&sg1,
      (void*)&l1w0, (void*)&l1b0, (void*)&l2w0, (void*)&l2b0,
      (void*)&l1w1, (void*)&l1b1, (void*)&l2w1, (void*)&l2b1,
      (void*)&bng0, (void*)&bnb0, (void*)&bng1, (void*)&bnb1,
      (void*)&fc1w, (void*)&fc1b, (void*)&fc2w, (void*)&fc2b,
      (void*)&out,
      (void*)&colb, (void*)&we0, (void*)&we1, (void*)&G, (void*)&h0,
      (void*)&bn, (void*)&sc, (void*)&fc1acc };
    hipError_t le = hipLaunchCooperativeKernel((const void*)fused_kernel,
                                               dim3(1024), dim3(256), args, 0, stream);
    if (le != hipSuccess) coop = false;
  }
  if (!coop) {
    // fallback: proven multi-kernel sequence (round-2 behavior)
    init_kernel<<<136, 256, 0, stream>>>(fc1acc, fc1b, bn);
    attn_kernel<<<16, 256, 0, stream>>>(pseudo, Lidx, edge_w, edge_b,
                                        mu0, sg0, mu1, sg1, we0, we1, colb);
    proj0_kernel<<<512, 256, 0, stream>>>(x, l1w0, l2w0, G);
    conv_kernel<<<4096, 256, 0, stream>>>(G, we0, colb, l1b0, l2b0,
                                          h0, bn, bn + 8192);
    bnfin_kernel<<<1, 256, 0, stream>>>(bn, bn + 8192, bng0, bnb0, sc, sc + 32);
    proj1_kernel<<<512, 256, 0, stream>>>(h0, sc, l1w1, l2w1, G);
    conv_kernel<<<4096, 256, 0, stream>>>(G, we1, colb, l1b1, l2b1,
                                          h0, bn + 16384, bn + 24576);
    bnfin_kernel<<<1, 256, 0, stream>>>(bn + 16384, bn + 24576, bng1, bnb1,
                                        sc + 64, sc + 96);
    fc1_kernel<<<1024, 256, 0, stream>>>(h0, sc + 64, fc1w, fc1acc);
    fc2_kernel<<<2, 256, 0, stream>>>(fc1acc, fc2w, fc2b, out);
  }
}